// Round 7
// baseline (123.013 us; speedup 1.0000x reference)
//
#include <hip/hip_runtime.h>
#include <math.h>

#define HID_DIM  512
#define HIDH_DIM 256
#define ZBLOCKS  125
#define UBLOCKS  128   // u-fold blocks: one wave per output k
#define JC       256

// ---------------------------------------------------------------------------
__device__ __forceinline__ float dot4(float4 a, float4 b) {
    return a.x * b.x + a.y * b.y + a.z * b.z + a.w * b.w;
}

// ---------------------------------------------------------------------------
// Fused prep:
//   [0,125)      : grid-stride zero of bond_corr
//   125          : edge-dtype probe + cvals reduction
//   [126,254)    : u-fold, one wave per k (coalesced float4 + butterfly)
//   [254,254+GB) : xg (SoA) gather
//   [..., +MB)   : mask/gpos via binary search over sorted gen_idx
__global__ __launch_bounds__(256) void prep_kernel(
        const unsigned int* __restrict__ ew,
        const float* __restrict__ Wp,  const float* __restrict__ bp,
        const float* __restrict__ wb,  const float* __restrict__ bb,
        const float* __restrict__ wv,  const float* __restrict__ bv,
        const int* __restrict__ gen_idx, const float* __restrict__ x_t,
        float4* __restrict__ zbase, int zcount,
        float* __restrict__ u_bond, float* __restrict__ u_val,
        float* __restrict__ cvals, int* __restrict__ flag,
        float* __restrict__ xgx, float* __restrict__ xgy, float* __restrict__ xgz,
        unsigned char* __restrict__ mask, int* __restrict__ gpos,
        int n, int G, int GB) {
    int b = blockIdx.x, t = threadIdx.x;
    if (b < ZBLOCKS) {
        const float4 z = make_float4(0.f, 0.f, 0.f, 0.f);
        for (int i = b * 256 + t; i < zcount; i += ZBLOCKS * 256) zbase[i] = z;
    } else if (b == ZBLOCKS) {
        if (t < 64) {  // wave 0: int64-vs-int32 edge layout probe
            unsigned int v = ew[2 * t + 1];
            unsigned long long bl = __ballot(v == 0u);
            if (t == 0) flag[0] = (bl == 0xFFFFFFFFFFFFFFFFULL) ? 1 : 0;
        }
        __shared__ float s1[256], s2[256];
        float p1 = (t < HIDH_DIM) ? bp[t] * wb[t] : 0.f;
        float p2 = (t < HIDH_DIM) ? bp[t] * wv[t] : 0.f;
        s1[t] = p1; s2[t] = p2;
        __syncthreads();
        for (int s = 128; s > 0; s >>= 1) {
            if (t < s) { s1[t] += s1[t + s]; s2[t] += s2[t + s]; }
            __syncthreads();
        }
        if (t == 0) { cvals[0] = s1[0] + bb[0]; cvals[1] = s2[0] + bv[0]; }
    } else if (b < ZBLOCKS + 1 + UBLOCKS) {
        // one wave per output k: lanes cover the 256-wide dot coalesced
        int w = t >> 6, lane = t & 63;
        int k = (b - ZBLOCKS - 1) * 4 + w;
        if (k < HID_DIM) {
            const float* wrow = Wp + (size_t)k * HIDH_DIM;
            float4 wr = *reinterpret_cast<const float4*>(wrow + lane * 4);
            float4 vb = *reinterpret_cast<const float4*>(wb + lane * 4);
            float4 vv = *reinterpret_cast<const float4*>(wv + lane * 4);
            float ub = dot4(wr, vb);
            float uv = dot4(wr, vv);
            #pragma unroll
            for (int off = 32; off > 0; off >>= 1) {
                ub += __shfl_down(ub, off, 64);
                uv += __shfl_down(uv, off, 64);
            }
            if (lane == 0) { u_bond[k] = ub; u_val[k] = uv; }
        }
    } else if (b < ZBLOCKS + 1 + UBLOCKS + GB) {
        int g = (b - ZBLOCKS - 1 - UBLOCKS) * 256 + t;
        if (g < G) {
            int idx = gen_idx[g];
            xgx[g] = x_t[3 * idx + 0];
            xgy[g] = x_t[3 * idx + 1];
            xgz[g] = x_t[3 * idx + 2];
        }
    } else {
        int base = ((b - ZBLOCKS - 1 - UBLOCKS - GB) * 256 + t) * 8;
        for (int k = 0; k < 8; ++k) {
            int i = base + k;
            if (i >= n) break;
            int lo = 0, hi = G - 1, g = -1;
            while (lo <= hi) {
                int mid = (lo + hi) >> 1;
                int v = gen_idx[mid];
                if (v == i) { g = mid; break; }
                if (v < i) lo = mid + 1; else hi = mid - 1;
            }
            mask[i] = (g >= 0) ? 1 : 0;
            if (g >= 0) gpos[i] = g;
        }
    }
}

// ---------------------------------------------------------------------------
// Mega kernel v3 — dispatch order: gate (BW-bound, starts streaming at t=0),
// bond (latency), clash (pure VALU, backfills the tail).
//   blocks [0, NBG)            : gates, 16 rows/block, 4 rows/wave, 8 loads deep
//   blocks [NBG, NBG+NBB)      : bond scatter
//   blocks [NBG+NBB, +NBC)     : clash -> float4 partial stores
__global__ __launch_bounds__(256) void mega_kernel(
        const float* __restrict__ H,
        const float* __restrict__ u_bond, const float* __restrict__ u_val,
        const float* __restrict__ cvals,
        const unsigned int* __restrict__ ew, const int* __restrict__ flag_p,
        const float* __restrict__ x_t, const unsigned char* __restrict__ mask,
        const float* __restrict__ xgx, const float* __restrict__ xgy,
        const float* __restrict__ xgz,
        float* __restrict__ bond_corr,
        float4* __restrict__ partials,
        float* __restrict__ bond_w, float* __restrict__ clash_w,
        int n, int E, int G, int NBG, int NBB, int CXB) {
    __shared__ __align__(16) float sx[JC];
    __shared__ __align__(16) float sy[JC];
    __shared__ __align__(16) float sz[JC];
    int b = blockIdx.x, t = threadIdx.x;

    if (b < NBG) {
        // ---- gates: 4 rows/wave, all 8 row-loads issued before reduction ----
        int w = t >> 6, lane = t & 63;
        int row0 = b * 16 + w * 4;
        if (row0 >= n) return;
        int o0 = lane * 4, o1 = 256 + lane * 4;
        const float* h0 = H + (size_t)row0 * HID_DIM;
        // 8 independent loads in flight (64B/lane = 4KB/wave)
        float4 a0 = *reinterpret_cast<const float4*>(h0 + o0);
        float4 a1 = *reinterpret_cast<const float4*>(h0 + o1);
        float4 b0 = *reinterpret_cast<const float4*>(h0 + HID_DIM + o0);
        float4 b1 = *reinterpret_cast<const float4*>(h0 + HID_DIM + o1);
        float4 c0 = *reinterpret_cast<const float4*>(h0 + 2 * HID_DIM + o0);
        float4 c1 = *reinterpret_cast<const float4*>(h0 + 2 * HID_DIM + o1);
        float4 d0 = *reinterpret_cast<const float4*>(h0 + 3 * HID_DIM + o0);
        float4 d1 = *reinterpret_cast<const float4*>(h0 + 3 * HID_DIM + o1);
        float4 ub0 = *reinterpret_cast<const float4*>(u_bond + o0);
        float4 ub1 = *reinterpret_cast<const float4*>(u_bond + o1);
        float4 uv0 = *reinterpret_cast<const float4*>(u_val + o0);
        float4 uv1 = *reinterpret_cast<const float4*>(u_val + o1);
        float sb0 = dot4(a0, ub0) + dot4(a1, ub1);
        float sv0 = dot4(a0, uv0) + dot4(a1, uv1);
        float sb1 = dot4(b0, ub0) + dot4(b1, ub1);
        float sv1 = dot4(b0, uv0) + dot4(b1, uv1);
        float sb2 = dot4(c0, ub0) + dot4(c1, ub1);
        float sv2 = dot4(c0, uv0) + dot4(c1, uv1);
        float sb3 = dot4(d0, ub0) + dot4(d1, ub1);
        float sv3 = dot4(d0, uv0) + dot4(d1, uv1);
        #pragma unroll
        for (int off = 32; off > 0; off >>= 1) {
            sb0 += __shfl_down(sb0, off, 64);
            sv0 += __shfl_down(sv0, off, 64);
            sb1 += __shfl_down(sb1, off, 64);
            sv1 += __shfl_down(sv1, off, 64);
            sb2 += __shfl_down(sb2, off, 64);
            sv2 += __shfl_down(sv2, off, 64);
            sb3 += __shfl_down(sb3, off, 64);
            sv3 += __shfl_down(sv3, off, 64);
        }
        if (lane == 0) {
            float cv0 = cvals[0], cv1 = cvals[1];
            bond_w [row0 + 0] = 1.f / (1.f + expf(-(sb0 + cv0)));
            clash_w[row0 + 0] = 1.f / (1.f + expf(-(sv0 + cv1)));
            if (row0 + 1 < n) {
                bond_w [row0 + 1] = 1.f / (1.f + expf(-(sb1 + cv0)));
                clash_w[row0 + 1] = 1.f / (1.f + expf(-(sv1 + cv1)));
            }
            if (row0 + 2 < n) {
                bond_w [row0 + 2] = 1.f / (1.f + expf(-(sb2 + cv0)));
                clash_w[row0 + 2] = 1.f / (1.f + expf(-(sv2 + cv1)));
            }
            if (row0 + 3 < n) {
                bond_w [row0 + 3] = 1.f / (1.f + expf(-(sb3 + cv0)));
                clash_w[row0 + 3] = 1.f / (1.f + expf(-(sv3 + cv1)));
            }
        }
    } else if (b < NBG + NBB) {
        // ---- bond scatter ----
        int e = (b - NBG) * 256 + t;
        if (e >= E) return;
        int f = flag_p[0];
        int row, col;
        if (f) {  // int64 layout: low words at even word indices
            row = (int)ew[2 * (size_t)e];
            col = (int)ew[2 * ((size_t)E + e)];
        } else {  // int32 layout
            row = (int)ew[e];
            col = (int)ew[(size_t)E + e];
        }
        if ((unsigned)row >= (unsigned)n || (unsigned)col >= (unsigned)n) return;
        if (!(mask[row] | mask[col])) return;
        float dx = x_t[3 * row + 0] - x_t[3 * col + 0];
        float dy = x_t[3 * row + 1] - x_t[3 * col + 1];
        float dz = x_t[3 * row + 2] - x_t[3 * col + 2];
        float d2 = dx * dx + dy * dy + dz * dz;
        float dist = sqrtf(fmaxf(d2, 1e-24f)) + 1e-8f;
        float s = (dist - 1.5f) / (dist * dist);
        float fx = s * dx, fy = s * dy, fz = s * dz;
        atomicAdd(&bond_corr[3 * row + 0],  fx);
        atomicAdd(&bond_corr[3 * row + 1],  fy);
        atomicAdd(&bond_corr[3 * row + 2],  fz);
        atomicAdd(&bond_corr[3 * col + 0], -fx);
        atomicAdd(&bond_corr[3 * col + 1], -fy);
        atomicAdd(&bond_corr[3 * col + 2], -fz);
    } else {
        // ---- clash: branchless; float4 partial per (yc,i) ----
        int b2 = b - NBG - NBB;
        int yc = b2 / CXB;
        int i  = (b2 - yc * CXB) * 256 + t;
        int j  = yc * JC + t;
        sx[t] = (j < G) ? xgx[j] : 1e30f;
        sy[t] = (j < G) ? xgy[j] : 1e30f;
        sz[t] = (j < G) ? xgz[j] : 1e30f;
        __syncthreads();
        if (i >= G) return;
        float xi = xgx[i], yi = xgy[i], zi = xgz[i];
        float csum = 0.f, cx = 0.f, cy = 0.f, cz = 0.f;
#define PROC(XS, YS, ZS) do {                                           \
            float dx = xi - (XS), dy = yi - (YS), dz = zi - (ZS);       \
            float d2 = fmaf(dx, dx, fmaf(dy, dy, dz * dz));             \
            float rm = __builtin_amdgcn_rsqf(d2);                       \
            float coef = fmaxf(fmaf(rm, rm, -rm), 0.0f);                \
            csum += coef;                                               \
            cx = fmaf(coef, (XS), cx);                                  \
            cy = fmaf(coef, (YS), cy);                                  \
            cz = fmaf(coef, (ZS), cz);                                  \
        } while (0)
        #pragma unroll 4
        for (int tt = 0; tt < JC; tt += 4) {
            float4 ax = *reinterpret_cast<const float4*>(&sx[tt]);
            float4 ay = *reinterpret_cast<const float4*>(&sy[tt]);
            float4 az = *reinterpret_cast<const float4*>(&sz[tt]);
            PROC(ax.x, ay.x, az.x);
            PROC(ax.y, ay.y, az.y);
            PROC(ax.z, ay.z, az.z);
            PROC(ax.w, ay.w, az.w);
        }
#undef PROC
        partials[(size_t)yc * G + i] = make_float4(csum, cx, cy, cz);
    }
}

// ---------------------------------------------------------------------------
// out = v_x - 0.1*bond_w*bond_corr - [mask] 0.05*clash_w*(xg*S - V),
// S,V summed from 32 coalesced float4 partials.
__global__ void final_kernel(const float* __restrict__ v_x,
                             const float* __restrict__ bond_w,
                             const float* __restrict__ clash_w,
                             const float* __restrict__ bond_corr,
                             const unsigned char* __restrict__ mask,
                             const int* __restrict__ gpos,
                             const float* __restrict__ xgx,
                             const float* __restrict__ xgy,
                             const float* __restrict__ xgz,
                             const float4* __restrict__ partials,
                             float* __restrict__ out, int n, int G, int NYC) {
    int i = blockIdx.x * blockDim.x + threadIdx.x;
    if (i >= n) return;
    float bw = 0.1f * bond_w[i];
    float ox = v_x[3 * i + 0] - bw * bond_corr[3 * i + 0];
    float oy = v_x[3 * i + 1] - bw * bond_corr[3 * i + 1];
    float oz = v_x[3 * i + 2] - bw * bond_corr[3 * i + 2];
    if (mask[i]) {
        int g = gpos[i];
        float s = 0.f, vx = 0.f, vy = 0.f, vz = 0.f;
        for (int yc = 0; yc < NYC; ++yc) {
            float4 p = partials[(size_t)yc * G + g];
            s += p.x; vx += p.y; vy += p.z; vz += p.w;
        }
        float cw = 0.05f * clash_w[i];
        ox -= cw * (xgx[g] * s - vx);
        oy -= cw * (xgy[g] * s - vy);
        oz -= cw * (xgz[g] * s - vz);
    }
    out[3 * i + 0] = ox;
    out[3 * i + 1] = oy;
    out[3 * i + 2] = oz;
}

// ---------------------------------------------------------------------------
extern "C" void kernel_launch(void* const* d_in, const int* in_sizes, int n_in,
                              void* d_out, int out_size, void* d_ws, size_t ws_size,
                              hipStream_t stream) {
    const float* v_x_raw = (const float*)d_in[0];
    const float* H       = (const float*)d_in[1];
    const float* x_t     = (const float*)d_in[2];
    const unsigned int* edges_w = (const unsigned int*)d_in[3];
    // d_in[4] = gen_mask (bool) — intentionally unused; rebuilt from gen_idx.
    const int* gen_idx   = (const int*)d_in[5];
    const float* W_proj  = (const float*)d_in[6];
    const float* b_proj  = (const float*)d_in[7];
    const float* w_bond  = (const float*)d_in[8];
    const float* b_bond  = (const float*)d_in[9];
    const float* w_val   = (const float*)d_in[10];
    const float* b_val   = (const float*)d_in[11];

    const int n = in_sizes[0] / 3;
    const int E = in_sizes[3] / 2;
    const int G = in_sizes[5];
    const int GB  = (G + 255) / 256;
    const int NYC = (G + JC - 1) / JC;   // clash y-chunks

    char* ws = (char*)d_ws;
    // --- zeroed region (bond_corr only) ---
    float* bond_corr = (float*)(ws);
    size_t zbytes = (size_t)n * 12;
    size_t off = (zbytes + 15) & ~(size_t)15;
    int zcount = (int)(off / 16);
    // --- write-every-launch region ---
    unsigned char* mask = (unsigned char*)(ws + off); off += ((size_t)n + 15) & ~(size_t)15;
    int*   gpos    = (int*)(ws + off);                off += (size_t)n * 4;
    float* bond_w  = (float*)(ws + off);              off += (size_t)n * 4;
    float* clash_w = (float*)(ws + off);              off += (size_t)n * 4;
    float* u_bond  = (float*)(ws + off);              off += HID_DIM * 4;
    float* u_val   = (float*)(ws + off);              off += HID_DIM * 4;
    float* cvals   = (float*)(ws + off);              off += 16;
    int*   flag    = (int*)(ws + off);                off += 16;
    float* xgx     = (float*)(ws + off);              off += (size_t)G * 4;
    float* xgy     = (float*)(ws + off);              off += (size_t)G * 4;
    float* xgz     = (float*)(ws + off);              off += (size_t)G * 4;
    float4* partials = (float4*)(ws + off);           off += (size_t)NYC * G * 16;

    const int MB  = (n + 2047) / 2048;   // mask/gpos blocks (8 idx/thread)
    const int CXB = GB;                   // clash x-blocks
    const int NBC = CXB * NYC;            // clash blocks
    const int NBG = (n + 15) / 16;        // gate blocks (16 rows each)
    const int NBB = (E + 255) / 256;      // bond blocks

    prep_kernel<<<ZBLOCKS + 1 + UBLOCKS + GB + MB, 256, 0, stream>>>(
        edges_w, W_proj, b_proj, w_bond, b_bond, w_val, b_val,
        gen_idx, x_t, (float4*)ws, zcount,
        u_bond, u_val, cvals, flag, xgx, xgy, xgz, mask, gpos, n, G, GB);

    mega_kernel<<<NBG + NBB + NBC, 256, 0, stream>>>(
        H, u_bond, u_val, cvals, edges_w, flag, x_t, mask,
        xgx, xgy, xgz, bond_corr, partials, bond_w, clash_w,
        n, E, G, NBG, NBB, CXB);

    final_kernel<<<(n + 255) / 256, 256, 0, stream>>>(
        v_x_raw, bond_w, clash_w, bond_corr, mask, gpos,
        xgx, xgy, xgz, partials, (float*)d_out, n, G, NYC);
}

// Round 8
// 98.864 us; speedup vs baseline: 1.2443x; 1.2443x over previous
//
#include <hip/hip_runtime.h>
#include <math.h>

#define HID_DIM  512
#define HIDH_DIM 256
#define ZBLOCKS  125
#define UBLOCKS  128   // u-fold blocks: one wave per output k
#define JC       256

// ---------------------------------------------------------------------------
__device__ __forceinline__ float dot4(float4 a, float4 b) {
    return a.x * b.x + a.y * b.y + a.z * b.z + a.w * b.w;
}

// ---------------------------------------------------------------------------
// Fused prep:
//   [0,125)      : grid-stride zero of bond_corr
//   125          : edge-dtype probe + cvals reduction
//   [126,254)    : u-fold, one wave per k (coalesced float4 + butterfly)
//   [254,254+GB) : xg (SoA) gather
//   [..., +MB)   : mask/gpos via binary search over sorted gen_idx
__global__ __launch_bounds__(256) void prep_kernel(
        const unsigned int* __restrict__ ew,
        const float* __restrict__ Wp,  const float* __restrict__ bp,
        const float* __restrict__ wb,  const float* __restrict__ bb,
        const float* __restrict__ wv,  const float* __restrict__ bv,
        const int* __restrict__ gen_idx, const float* __restrict__ x_t,
        float4* __restrict__ zbase, int zcount,
        float* __restrict__ u_bond, float* __restrict__ u_val,
        float* __restrict__ cvals, int* __restrict__ flag,
        float* __restrict__ xgx, float* __restrict__ xgy, float* __restrict__ xgz,
        unsigned char* __restrict__ mask, int* __restrict__ gpos,
        int n, int G, int GB) {
    int b = blockIdx.x, t = threadIdx.x;
    if (b < ZBLOCKS) {
        const float4 z = make_float4(0.f, 0.f, 0.f, 0.f);
        for (int i = b * 256 + t; i < zcount; i += ZBLOCKS * 256) zbase[i] = z;
    } else if (b == ZBLOCKS) {
        if (t < 64) {  // wave 0: int64-vs-int32 edge layout probe
            unsigned int v = ew[2 * t + 1];
            unsigned long long bl = __ballot(v == 0u);
            if (t == 0) flag[0] = (bl == 0xFFFFFFFFFFFFFFFFULL) ? 1 : 0;
        }
        __shared__ float s1[256], s2[256];
        float p1 = (t < HIDH_DIM) ? bp[t] * wb[t] : 0.f;
        float p2 = (t < HIDH_DIM) ? bp[t] * wv[t] : 0.f;
        s1[t] = p1; s2[t] = p2;
        __syncthreads();
        for (int s = 128; s > 0; s >>= 1) {
            if (t < s) { s1[t] += s1[t + s]; s2[t] += s2[t + s]; }
            __syncthreads();
        }
        if (t == 0) { cvals[0] = s1[0] + bb[0]; cvals[1] = s2[0] + bv[0]; }
    } else if (b < ZBLOCKS + 1 + UBLOCKS) {
        // one wave per output k: lanes cover the 256-wide dot coalesced
        int w = t >> 6, lane = t & 63;
        int k = (b - ZBLOCKS - 1) * 4 + w;
        if (k < HID_DIM) {
            const float* wrow = Wp + (size_t)k * HIDH_DIM;
            float4 wr = *reinterpret_cast<const float4*>(wrow + lane * 4);
            float4 vb = *reinterpret_cast<const float4*>(wb + lane * 4);
            float4 vv = *reinterpret_cast<const float4*>(wv + lane * 4);
            float ub = dot4(wr, vb);
            float uv = dot4(wr, vv);
            #pragma unroll
            for (int off = 32; off > 0; off >>= 1) {
                ub += __shfl_down(ub, off, 64);
                uv += __shfl_down(uv, off, 64);
            }
            if (lane == 0) { u_bond[k] = ub; u_val[k] = uv; }
        }
    } else if (b < ZBLOCKS + 1 + UBLOCKS + GB) {
        int g = (b - ZBLOCKS - 1 - UBLOCKS) * 256 + t;
        if (g < G) {
            int idx = gen_idx[g];
            xgx[g] = x_t[3 * idx + 0];
            xgy[g] = x_t[3 * idx + 1];
            xgz[g] = x_t[3 * idx + 2];
        }
    } else {
        int base = ((b - ZBLOCKS - 1 - UBLOCKS - GB) * 256 + t) * 8;
        for (int k = 0; k < 8; ++k) {
            int i = base + k;
            if (i >= n) break;
            int lo = 0, hi = G - 1, g = -1;
            while (lo <= hi) {
                int mid = (lo + hi) >> 1;
                int v = gen_idx[mid];
                if (v == i) { g = mid; break; }
                if (v < i) lo = mid + 1; else hi = mid - 1;
            }
            mask[i] = (g >= 0) ? 1 : 0;
            if (g >= 0) gpos[i] = g;
        }
    }
}

// ---------------------------------------------------------------------------
// Mega kernel v4 — STRIPED role assignment: block b%5 in {0,1}->gate,
// {2,3}->bond, {4}->clash (ratio 2:2:1 matches NBG:NBB:NBC=2048:2048:1024),
// so every co-resident scheduling window holds a mix of BW-bound, latency-
// bound and VALU-bound waves for the whole dispatch.
__global__ __launch_bounds__(256) void mega_kernel(
        const float* __restrict__ H,
        const float* __restrict__ u_bond, const float* __restrict__ u_val,
        const float* __restrict__ cvals,
        const unsigned int* __restrict__ ew, const int* __restrict__ flag_p,
        const float* __restrict__ x_t, const unsigned char* __restrict__ mask,
        const float* __restrict__ xgx, const float* __restrict__ xgy,
        const float* __restrict__ xgz,
        float* __restrict__ bond_corr,
        float4* __restrict__ partials,
        float* __restrict__ bond_w, float* __restrict__ clash_w,
        int n, int E, int G, int NBG, int NBB, int NBC, int CXB) {
    __shared__ __align__(16) float sx[JC];
    __shared__ __align__(16) float sy[JC];
    __shared__ __align__(16) float sz[JC];
    int b = blockIdx.x, t = threadIdx.x;
    int stripe = b / 5, role = b - stripe * 5;

    if (role < 2) {
        // ---- gates: 32 rows/block, 8 rows/wave, u hoisted to registers ----
        int bb = stripe * 2 + role;
        if (bb >= NBG) return;
        int w = t >> 6, lane = t & 63;
        int row0 = bb * 32 + w * 8;
        int o0 = lane * 4, o1 = 256 + lane * 4;
        float4 ub0 = *reinterpret_cast<const float4*>(u_bond + o0);
        float4 ub1 = *reinterpret_cast<const float4*>(u_bond + o1);
        float4 uv0 = *reinterpret_cast<const float4*>(u_val + o0);
        float4 uv1 = *reinterpret_cast<const float4*>(u_val + o1);
        float c0 = cvals[0], c1 = cvals[1];
        #pragma unroll
        for (int r = 0; r < 8; r += 2) {
            int ra = row0 + r, rb = ra + 1;
            bool va = (ra < n), vb = (rb < n);
            const float* ha = H + (size_t)(va ? ra : 0) * HID_DIM;
            const float* hb = H + (size_t)(vb ? rb : 0) * HID_DIM;
            float4 a0 = *reinterpret_cast<const float4*>(ha + o0);
            float4 a1 = *reinterpret_cast<const float4*>(ha + o1);
            float4 b0 = *reinterpret_cast<const float4*>(hb + o0);
            float4 b1 = *reinterpret_cast<const float4*>(hb + o1);
            float sba = dot4(a0, ub0) + dot4(a1, ub1);
            float sva = dot4(a0, uv0) + dot4(a1, uv1);
            float sbb = dot4(b0, ub0) + dot4(b1, ub1);
            float svb = dot4(b0, uv0) + dot4(b1, uv1);
            #pragma unroll
            for (int off = 32; off > 0; off >>= 1) {
                sba += __shfl_down(sba, off, 64);
                sva += __shfl_down(sva, off, 64);
                sbb += __shfl_down(sbb, off, 64);
                svb += __shfl_down(svb, off, 64);
            }
            if (lane == 0) {
                if (va) {
                    bond_w[ra]  = 1.f / (1.f + expf(-(sba + c0)));
                    clash_w[ra] = 1.f / (1.f + expf(-(sva + c1)));
                }
                if (vb) {
                    bond_w[rb]  = 1.f / (1.f + expf(-(sbb + c0)));
                    clash_w[rb] = 1.f / (1.f + expf(-(svb + c1)));
                }
            }
        }
    } else if (role < 4) {
        // ---- bond scatter ----
        int e = (stripe * 2 + role - 2) * 256 + t;
        if (e >= E) return;
        int f = flag_p[0];
        int row, col;
        if (f) {  // int64 layout: low words at even word indices
            row = (int)ew[2 * (size_t)e];
            col = (int)ew[2 * ((size_t)E + e)];
        } else {  // int32 layout
            row = (int)ew[e];
            col = (int)ew[(size_t)E + e];
        }
        if ((unsigned)row >= (unsigned)n || (unsigned)col >= (unsigned)n) return;
        if (!(mask[row] | mask[col])) return;
        float dx = x_t[3 * row + 0] - x_t[3 * col + 0];
        float dy = x_t[3 * row + 1] - x_t[3 * col + 1];
        float dz = x_t[3 * row + 2] - x_t[3 * col + 2];
        float d2 = dx * dx + dy * dy + dz * dz;
        float dist = sqrtf(fmaxf(d2, 1e-24f)) + 1e-8f;
        float s = (dist - 1.5f) / (dist * dist);
        float fx = s * dx, fy = s * dy, fz = s * dz;
        atomicAdd(&bond_corr[3 * row + 0],  fx);
        atomicAdd(&bond_corr[3 * row + 1],  fy);
        atomicAdd(&bond_corr[3 * row + 2],  fz);
        atomicAdd(&bond_corr[3 * col + 0], -fx);
        atomicAdd(&bond_corr[3 * col + 1], -fy);
        atomicAdd(&bond_corr[3 * col + 2], -fz);
    } else {
        // ---- clash: branchless; float4 partial per (yc,i) ----
        int b2 = stripe;
        if (b2 >= NBC) return;
        int yc = b2 / CXB;
        int i  = (b2 - yc * CXB) * 256 + t;
        int j  = yc * JC + t;
        sx[t] = (j < G) ? xgx[j] : 1e30f;
        sy[t] = (j < G) ? xgy[j] : 1e30f;
        sz[t] = (j < G) ? xgz[j] : 1e30f;
        __syncthreads();
        if (i >= G) return;
        float xi = xgx[i], yi = xgy[i], zi = xgz[i];
        float csum = 0.f, cx = 0.f, cy = 0.f, cz = 0.f;
#define PROC(XS, YS, ZS) do {                                           \
            float dx = xi - (XS), dy = yi - (YS), dz = zi - (ZS);       \
            float d2 = fmaf(dx, dx, fmaf(dy, dy, dz * dz));             \
            float rm = __builtin_amdgcn_rsqf(d2);                       \
            float coef = fmaxf(fmaf(rm, rm, -rm), 0.0f);                \
            csum += coef;                                               \
            cx = fmaf(coef, (XS), cx);                                  \
            cy = fmaf(coef, (YS), cy);                                  \
            cz = fmaf(coef, (ZS), cz);                                  \
        } while (0)
        #pragma unroll 4
        for (int tt = 0; tt < JC; tt += 4) {
            float4 ax = *reinterpret_cast<const float4*>(&sx[tt]);
            float4 ay = *reinterpret_cast<const float4*>(&sy[tt]);
            float4 az = *reinterpret_cast<const float4*>(&sz[tt]);
            PROC(ax.x, ay.x, az.x);
            PROC(ax.y, ay.y, az.y);
            PROC(ax.z, ay.z, az.z);
            PROC(ax.w, ay.w, az.w);
        }
#undef PROC
        partials[(size_t)yc * G + i] = make_float4(csum, cx, cy, cz);
    }
}

// ---------------------------------------------------------------------------
// out = v_x - 0.1*bond_w*bond_corr - [mask] 0.05*clash_w*(xg*S - V),
// S,V summed from 32 coalesced float4 partials.
__global__ void final_kernel(const float* __restrict__ v_x,
                             const float* __restrict__ bond_w,
                             const float* __restrict__ clash_w,
                             const float* __restrict__ bond_corr,
                             const unsigned char* __restrict__ mask,
                             const int* __restrict__ gpos,
                             const float* __restrict__ xgx,
                             const float* __restrict__ xgy,
                             const float* __restrict__ xgz,
                             const float4* __restrict__ partials,
                             float* __restrict__ out, int n, int G, int NYC) {
    int i = blockIdx.x * blockDim.x + threadIdx.x;
    if (i >= n) return;
    float bw = 0.1f * bond_w[i];
    float ox = v_x[3 * i + 0] - bw * bond_corr[3 * i + 0];
    float oy = v_x[3 * i + 1] - bw * bond_corr[3 * i + 1];
    float oz = v_x[3 * i + 2] - bw * bond_corr[3 * i + 2];
    if (mask[i]) {
        int g = gpos[i];
        float s = 0.f, vx = 0.f, vy = 0.f, vz = 0.f;
        for (int yc = 0; yc < NYC; ++yc) {
            float4 p = partials[(size_t)yc * G + g];
            s += p.x; vx += p.y; vy += p.z; vz += p.w;
        }
        float cw = 0.05f * clash_w[i];
        ox -= cw * (xgx[g] * s - vx);
        oy -= cw * (xgy[g] * s - vy);
        oz -= cw * (xgz[g] * s - vz);
    }
    out[3 * i + 0] = ox;
    out[3 * i + 1] = oy;
    out[3 * i + 2] = oz;
}

// ---------------------------------------------------------------------------
extern "C" void kernel_launch(void* const* d_in, const int* in_sizes, int n_in,
                              void* d_out, int out_size, void* d_ws, size_t ws_size,
                              hipStream_t stream) {
    const float* v_x_raw = (const float*)d_in[0];
    const float* H       = (const float*)d_in[1];
    const float* x_t     = (const float*)d_in[2];
    const unsigned int* edges_w = (const unsigned int*)d_in[3];
    // d_in[4] = gen_mask (bool) — intentionally unused; rebuilt from gen_idx.
    const int* gen_idx   = (const int*)d_in[5];
    const float* W_proj  = (const float*)d_in[6];
    const float* b_proj  = (const float*)d_in[7];
    const float* w_bond  = (const float*)d_in[8];
    const float* b_bond  = (const float*)d_in[9];
    const float* w_val   = (const float*)d_in[10];
    const float* b_val   = (const float*)d_in[11];

    const int n = in_sizes[0] / 3;
    const int E = in_sizes[3] / 2;
    const int G = in_sizes[5];
    const int GB  = (G + 255) / 256;
    const int NYC = (G + JC - 1) / JC;   // clash y-chunks

    char* ws = (char*)d_ws;
    // --- zeroed region (bond_corr only) ---
    float* bond_corr = (float*)(ws);
    size_t zbytes = (size_t)n * 12;
    size_t off = (zbytes + 15) & ~(size_t)15;
    int zcount = (int)(off / 16);
    // --- write-every-launch region ---
    unsigned char* mask = (unsigned char*)(ws + off); off += ((size_t)n + 15) & ~(size_t)15;
    int*   gpos    = (int*)(ws + off);                off += (size_t)n * 4;
    float* bond_w  = (float*)(ws + off);              off += (size_t)n * 4;
    float* clash_w = (float*)(ws + off);              off += (size_t)n * 4;
    float* u_bond  = (float*)(ws + off);              off += HID_DIM * 4;
    float* u_val   = (float*)(ws + off);              off += HID_DIM * 4;
    float* cvals   = (float*)(ws + off);              off += 16;
    int*   flag    = (int*)(ws + off);                off += 16;
    float* xgx     = (float*)(ws + off);              off += (size_t)G * 4;
    float* xgy     = (float*)(ws + off);              off += (size_t)G * 4;
    float* xgz     = (float*)(ws + off);              off += (size_t)G * 4;
    float4* partials = (float4*)(ws + off);           off += (size_t)NYC * G * 16;

    const int MB  = (n + 2047) / 2048;   // mask/gpos blocks (8 idx/thread)
    const int CXB = GB;                   // clash x-blocks
    const int NBC = CXB * NYC;            // clash blocks
    const int NBG = (n + 31) / 32;        // gate blocks (32 rows each)
    const int NBB = (E + 255) / 256;      // bond blocks

    // stripes: each stripe = 2 gate + 2 bond + 1 clash blocks
    int S = (NBG + 1) / 2;
    if ((NBB + 1) / 2 > S) S = (NBB + 1) / 2;
    if (NBC > S) S = NBC;

    prep_kernel<<<ZBLOCKS + 1 + UBLOCKS + GB + MB, 256, 0, stream>>>(
        edges_w, W_proj, b_proj, w_bond, b_bond, w_val, b_val,
        gen_idx, x_t, (float4*)ws, zcount,
        u_bond, u_val, cvals, flag, xgx, xgy, xgz, mask, gpos, n, G, GB);

    mega_kernel<<<S * 5, 256, 0, stream>>>(
        H, u_bond, u_val, cvals, edges_w, flag, x_t, mask,
        xgx, xgy, xgz, bond_corr, partials, bond_w, clash_w,
        n, E, G, NBG, NBB, NBC, CXB);

    final_kernel<<<(n + 255) / 256, 256, 0, stream>>>(
        v_x_raw, bond_w, clash_w, bond_corr, mask, gpos,
        xgx, xgy, xgz, partials, (float*)d_out, n, G, NYC);
}